// Round 5
// baseline (185.184 us; speedup 1.0000x reference)
//
#include <hip/hip_runtime.h>
#include <math.h>

// Problem: B=64, T=512, D=1024.
//   v[b,d]     = sum_e W[d,e] * x[b,T-1,e]
//   scores[b,t]= sum_d x[b,t,d] * v[b,d]          (t in 0..510)
//   alpha      = softmax_t(scores)
//   c[b,d]     = sum_t alpha[b,t] * x[b,t,d]
//   out[b]     = concat(c[b,:], x[b,T-1,:])       (64 x 2048 fp32)

#define BB 64
#define TT 512
#define DD 1024
#define TH 511           // valid history rows: 0..510
#define GROUPS 16        // blocks per batch
#define RPW 8            // rows per wave (4 waves * 8 = 32 rows per block)

// workspace (floats):
//   v      : [BB][DD]          off 0
//   partC  : [BB][GROUPS][DD]  off 65536
//   partML : [BB][GROUPS][2]   off 1114112
//   cnt    : [BB] ints         off 1116160

__device__ __forceinline__ float dot16(const float4* a, const float4* b) {
    float s = 0.f;
#pragma unroll
    for (int j = 0; j < 4; ++j)
        s += a[j].x * b[j].x + a[j].y * b[j].y + a[j].z * b[j].z + a[j].w * b[j].w;
    return s;
}

// ---------------- kernel 1: v = x_last @ W^T (+ zero finalize counters) ----
// 256 blocks x 4 waves; wave = 4 d-rows x 16 batches, batches in pairs (ILP 8).
__global__ __launch_bounds__(256) void k_v(const float* __restrict__ x,
                                           const float* __restrict__ W,
                                           float* __restrict__ v,
                                           int* __restrict__ cnt) {
    if (blockIdx.x == 0 && threadIdx.x < BB) cnt[threadIdx.x] = 0;

    const int wave = threadIdx.x >> 6;
    const int lane = threadIdx.x & 63;
    const int wg   = blockIdx.x * 4 + wave;   // 0..1023
    const int d0   = (wg >> 2) * 4;           // 256 d-quads
    const int bg   = wg & 3;                  // 4 batch-groups of 16

    float4 w4[4][4];
#pragma unroll
    for (int k = 0; k < 4; ++k)
#pragma unroll
        for (int j = 0; j < 4; ++j)
            w4[k][j] = *(const float4*)(W + (size_t)(d0 + k) * DD + j * 256 + lane * 4);

    float res = 0.f;                          // lane l -> (b = bg*16+(l>>2), d = d0+(l&3))
#pragma unroll
    for (int ip = 0; ip < 8; ++ip) {
        const int i0 = ip * 2;
        const float* xl0 = x + ((size_t)(bg * 16 + i0) * TT + (TT - 1)) * DD;
        const float* xl1 = xl0 + (size_t)TT * DD;
        float4 xA[4], xB[4];
#pragma unroll
        for (int j = 0; j < 4; ++j) {
            xA[j] = *(const float4*)(xl0 + j * 256 + lane * 4);
            xB[j] = *(const float4*)(xl1 + j * 256 + lane * 4);
        }
        float pA[4], pB[4];
#pragma unroll
        for (int k = 0; k < 4; ++k) {
            pA[k] = dot16(w4[k], xA);
            pB[k] = dot16(w4[k], xB);
        }
#pragma unroll
        for (int mm = 1; mm < 64; mm <<= 1) {
#pragma unroll
            for (int k = 0; k < 4; ++k) {
                pA[k] += __shfl_xor(pA[k], mm, 64);
                pB[k] += __shfl_xor(pB[k], mm, 64);
            }
        }
#pragma unroll
        for (int k = 0; k < 4; ++k) {
            if (lane == i0 * 4 + k)       res = pA[k];
            if (lane == (i0 + 1) * 4 + k) res = pB[k];
        }
    }
    v[(size_t)(bg * 16 + (lane >> 2)) * DD + d0 + (lane & 3)] = res;
}

// ---------------- kernel 2: wave-autonomous flash + fused finalize ---------
// 1024 blocks (64 b x 16 groups), 256 thr. Wave: 8 rows in pairs, online
// softmax in registers, pair-deep prefetch, no barriers in hot loop.
// Last block per batch combines the 16 partials and writes out.
__global__ __launch_bounds__(256) void k_chunk(const float* __restrict__ x,
                                               const float* __restrict__ v,
                                               float* __restrict__ partC,
                                               float* __restrict__ partML,
                                               int* __restrict__ cnt,
                                               float* __restrict__ out) {
    __shared__ float cw[4][DD];               // 16 KB combine buffer
    __shared__ float cml[4][2];
    __shared__ float sm[GROUPS], sl[GROUPS];
    __shared__ int   done;

    const int b    = blockIdx.x >> 4;
    const int g    = blockIdx.x & (GROUPS - 1);
    const int wave = threadIdx.x >> 6;
    const int lane = threadIdx.x & 63;
    const int r0   = g * 32 + wave * RPW;     // <= 504
    const int col  = lane * 4;

    const float* xb = x + (size_t)b * TT * DD;

    float4 v4[4];
#pragma unroll
    for (int j = 0; j < 4; ++j)
        v4[j] = *(const float4*)(v + (size_t)b * DD + j * 256 + col);

#define LOADROW(dst, r) do { const float* _p = xb + (size_t)(r) * DD + col;   \
        dst[0] = *(const float4*)(_p);       dst[1] = *(const float4*)(_p + 256); \
        dst[2] = *(const float4*)(_p + 512); dst[3] = *(const float4*)(_p + 768); } while (0)

    float4 bA[4], bB[4], bC[4], bD[4];
    LOADROW(bA, r0);
    LOADROW(bB, r0 + 1);

    float m = -INFINITY, l = 0.f;
    float4 acc[4] = {make_float4(0,0,0,0), make_float4(0,0,0,0),
                     make_float4(0,0,0,0), make_float4(0,0,0,0)};

#pragma unroll
    for (int p = 0; p < 4; ++p) {
        float4* ca = (p & 1) ? bC : bA;
        float4* cb = (p & 1) ? bD : bB;
        float4* na = (p & 1) ? bA : bC;
        float4* nb = (p & 1) ? bB : bD;
        if (p < 3) {                          // prefetch next pair (clamped)
            LOADROW(na, min(r0 + 2 * p + 2, TH - 1));
            LOADROW(nb, min(r0 + 2 * p + 3, TH - 1));
        }
        float s0 = dot16(v4, ca);
        float s1 = dot16(v4, cb);
#pragma unroll
        for (int mm = 1; mm < 64; mm <<= 1) {
            s0 += __shfl_xor(s0, mm, 64);
            s1 += __shfl_xor(s1, mm, 64);
        }
        if (r0 + 2 * p     >= TH) s0 = -INFINITY;   // only possible in last pair
        if (r0 + 2 * p + 1 >= TH) s1 = -INFINITY;

        const float mn = fmaxf(m, fmaxf(s0, s1));
        if (mn > m) {                         // wave-uniform (butterfly output)
            const float sc = __expf(m - mn);  // first pair: exp(-inf)=0
#pragma unroll
            for (int j = 0; j < 4; ++j) {
                acc[j].x *= sc; acc[j].y *= sc; acc[j].z *= sc; acc[j].w *= sc;
            }
            l *= sc;
            m = mn;
        }
        const float e0 = __expf(s0 - m);
        const float e1 = __expf(s1 - m);
        l += e0 + e1;
#pragma unroll
        for (int j = 0; j < 4; ++j) {
            acc[j].x += e0 * ca[j].x + e1 * cb[j].x;
            acc[j].y += e0 * ca[j].y + e1 * cb[j].y;
            acc[j].z += e0 * ca[j].z + e1 * cb[j].z;
            acc[j].w += e0 * ca[j].w + e1 * cb[j].w;
        }
    }
#undef LOADROW

    // one cross-wave combine per block
#pragma unroll
    for (int j = 0; j < 4; ++j)
        *(float4*)(&cw[wave][j * 256 + col]) = acc[j];
    if (lane == 0) { cml[wave][0] = m; cml[wave][1] = l; }
    __syncthreads();

    const float M = fmaxf(fmaxf(cml[0][0], cml[1][0]), fmaxf(cml[2][0], cml[3][0]));
    const float w0 = __expf(cml[0][0] - M), w1 = __expf(cml[1][0] - M);
    const float w2 = __expf(cml[2][0] - M), w3 = __expf(cml[3][0] - M);
    const float L = w0 * cml[0][1] + w1 * cml[1][1] + w2 * cml[2][1] + w3 * cml[3][1];

    const int d0 = threadIdx.x * 4;
    {
        const float4 s0 = *(const float4*)(&cw[0][d0]);
        const float4 s1 = *(const float4*)(&cw[1][d0]);
        const float4 s2 = *(const float4*)(&cw[2][d0]);
        const float4 s3 = *(const float4*)(&cw[3][d0]);
        float4 o;
        o.x = w0 * s0.x + w1 * s1.x + w2 * s2.x + w3 * s3.x;
        o.y = w0 * s0.y + w1 * s1.y + w2 * s2.y + w3 * s3.y;
        o.z = w0 * s0.z + w1 * s1.z + w2 * s2.z + w3 * s3.z;
        o.w = w0 * s0.w + w1 * s1.w + w2 * s2.w + w3 * s3.w;
        *(float4*)(partC + ((size_t)b * GROUPS + g) * DD + d0) = o;
    }
    if (threadIdx.x == 0) {
        partML[((size_t)b * GROUPS + g) * 2 + 0] = M;
        partML[((size_t)b * GROUPS + g) * 2 + 1] = L;
    }
    __threadfence();                          // release partials (device scope)
    __syncthreads();
    if (threadIdx.x == 0) {
        const int r = atomicAdd(&cnt[b], 1);
        done = (r == GROUPS - 1);
    }
    __syncthreads();
    if (!done) return;

    // ---- finalize (last block of this batch) ----
    __threadfence();                          // acquire partials
    if (threadIdx.x < GROUPS) {
        sm[threadIdx.x] = partML[((size_t)b * GROUPS + threadIdx.x) * 2 + 0];
        sl[threadIdx.x] = partML[((size_t)b * GROUPS + threadIdx.x) * 2 + 1];
    }
    __syncthreads();

    float Mg = -INFINITY;
#pragma unroll
    for (int g2 = 0; g2 < GROUPS; ++g2) Mg = fmaxf(Mg, sm[g2]);
    float wgt[GROUPS];
    float Lg = 0.f;
#pragma unroll
    for (int g2 = 0; g2 < GROUPS; ++g2) {
        wgt[g2] = __expf(sm[g2] - Mg);
        Lg += wgt[g2] * sl[g2];
    }
    const float invL = 1.f / Lg;

    float4 a = make_float4(0.f, 0.f, 0.f, 0.f);
#pragma unroll
    for (int g2 = 0; g2 < GROUPS; ++g2) {
        const float4 pc = *(const float4*)(partC + ((size_t)b * GROUPS + g2) * DD + d0);
        a.x += wgt[g2] * pc.x; a.y += wgt[g2] * pc.y;
        a.z += wgt[g2] * pc.z; a.w += wgt[g2] * pc.w;
    }
    a.x *= invL; a.y *= invL; a.z *= invL; a.w *= invL;
    *(float4*)(out + (size_t)b * 2048 + d0) = a;

    const float4 xl = *(const float4*)(xb + (size_t)(TT - 1) * DD + d0);
    *(float4*)(out + (size_t)b * 2048 + 1024 + d0) = xl;
}

extern "C" void kernel_launch(void* const* d_in, const int* in_sizes, int n_in,
                              void* d_out, int out_size, void* d_ws, size_t ws_size,
                              hipStream_t stream) {
    const float* x = (const float*)d_in[0];   // (64,512,1024) fp32
    const float* W = (const float*)d_in[1];   // (1024,1024) fp32
    float* out = (float*)d_out;               // (64,2048) fp32

    float* ws     = (float*)d_ws;
    float* v      = ws;                                           // 65536
    float* partC  = ws + 65536;                                   // 1048576
    float* partML = ws + 65536 + (size_t)BB * GROUPS * DD;        // 2048
    int*   cnt    = (int*)(partML + (size_t)BB * GROUPS * 2);     // 64 ints

    k_v<<<256, 256, 0, stream>>>(x, W, v, cnt);
    k_chunk<<<BB * GROUPS, 256, 0, stream>>>(x, v, partC, partML, cnt, out);
}